// Round 1
// baseline (304.903 us; speedup 1.0000x reference)
//
#include <hip/hip_runtime.h>
#include <stdint.h>

#define XDIM 131
#define LATENT 128
#define FDIM 32
#define GSZ 513
#define HID 256
#define SDF_IN 227

typedef __attribute__((ext_vector_type(8))) short bf16x8;
typedef __attribute__((ext_vector_type(4))) float f32x4;
typedef unsigned short ushort_t;
typedef unsigned int uint32;

__device__ __forceinline__ unsigned short f2bf(float f) {
  uint32 u = __float_as_uint(f);
  u += 0x7fffu + ((u >> 16) & 1u);   // RTNE
  return (unsigned short)(u >> 16);
}
__device__ __forceinline__ float bf2f(unsigned short s) {
  return __uint_as_float(((uint32)s) << 16);
}

// ---------------- prep: P [3][32][513][513] f32 -> Pt [3][513][513][32] bf16
__global__ void prep_pt(const float* __restrict__ P, unsigned short* __restrict__ Pt) {
  int i = blockIdx.x * 256 + threadIdx.x;
  const int CELLS = 3 * GSZ * GSZ;
  if (i >= CELLS) return;
  int pl = i / (GSZ * GSZ);
  int yx = i - pl * (GSZ * GSZ);
  const float* src = P + (size_t)pl * FDIM * GSZ * GSZ + yx;
  union { unsigned short u[32]; uint4 v[4]; } t;
#pragma unroll
  for (int c = 0; c < 32; ++c)
    t.u[c] = f2bf(src[(size_t)c * (GSZ * GSZ)]);
  uint4* dst = (uint4*)(Pt + (size_t)i * 32);
#pragma unroll
  for (int w = 0; w < 4; ++w) dst[w] = t.v[w];
}

// ---------------- prep: W0/W1 f32 -> bf16 in MFMA B-frag order [kb][g][n][8]
__global__ void prep_w(const float* __restrict__ W0, const float* __restrict__ W1,
                       unsigned short* __restrict__ W0g, unsigned short* __restrict__ W1g) {
  int i = blockIdx.x * 256 + threadIdx.x;  // 0..16383
  int sel = i >> 13;
  int t = i & 8191;
  int ks = t >> 10;
  int g  = (t >> 8) & 3;
  int n  = t & 255;
  union { unsigned short u[8]; uint4 v; } o;
#pragma unroll
  for (int j = 0; j < 8; ++j) {
    int k = ks * 32 + g * 8 + j;
    float val;
    if (sel == 0) val = (k < SDF_IN) ? W0[k * 256 + n] : 0.f;
    else          val = W1[k * 256 + n];
    o.u[j] = f2bf(val);
  }
  unsigned short* dst = (sel == 0 ? W0g : W1g) + (size_t)t * 8;
  *(uint4*)dst = o.v;
}

// LDS layout for activations: element (r, c) at  ((c>>5)*4 + ((c>>3)&3))*1024 + r*8 + (c&7)
// -> A-frag ds_read_b128 is 16 contiguous B per lane, conflict-free.
__device__ __forceinline__ int act_addr(int r, int c) {
  return ((c >> 5) * 4 + ((c >> 3) & 3)) * 1024 + r * 8 + (c & 7);
}

__device__ __forceinline__ void gemm_layer(unsigned short* act,
                                           const unsigned short* __restrict__ Wg,
                                           const float* __restrict__ bias,
                                           int rg, int cg, int lr, int lg)
{
  f32x4 acc[4][4];
#pragma unroll
  for (int mf = 0; mf < 4; ++mf)
#pragma unroll
    for (int nf = 0; nf < 4; ++nf) acc[mf][nf] = (f32x4){0.f, 0.f, 0.f, 0.f};

  float bs[4];
#pragma unroll
  for (int nf = 0; nf < 4; ++nf) bs[nf] = bias[cg * 64 + nf * 16 + lr];

#pragma unroll
  for (int kb = 0; kb < 8; ++kb) {
    bf16x8 a[4], b[4];
#pragma unroll
    for (int mf = 0; mf < 4; ++mf)
      a[mf] = *(const bf16x8*)(act + kb * 4096 + lg * 1024 + (rg * 64 + mf * 16 + lr) * 8);
#pragma unroll
    for (int nf = 0; nf < 4; ++nf)
      b[nf] = *(const bf16x8*)(Wg + (size_t)(kb * 4 + lg) * 2048 + (cg * 64 + nf * 16 + lr) * 8);
#pragma unroll
    for (int mf = 0; mf < 4; ++mf)
#pragma unroll
      for (int nf = 0; nf < 4; ++nf)
        acc[mf][nf] = __builtin_amdgcn_mfma_f32_16x16x32_bf16(a[mf], b[nf], acc[mf][nf], 0, 0, 0);
  }
  __syncthreads();   // everyone done reading act before we overwrite with h
#pragma unroll
  for (int mf = 0; mf < 4; ++mf)
#pragma unroll
    for (int nf = 0; nf < 4; ++nf) {
      int c = cg * 64 + nf * 16 + lr;
      unsigned short* dst = act + ((c >> 5) * 4 + ((c >> 3) & 3)) * 1024 + (c & 7);
#pragma unroll
      for (int reg = 0; reg < 4; ++reg) {
        int r = rg * 64 + mf * 16 + lg * 4 + reg;
        float vv = fmaxf(acc[mf][nf][reg] + bs[nf], 0.f);
        dst[r * 8] = f2bf(vv);
      }
    }
  __syncthreads();
}

template<int USE_PT>
__global__ __launch_bounds__(512) void sdf_main(
    const float* __restrict__ x, const float* __restrict__ P,
    const unsigned short* __restrict__ Pt,
    const unsigned short* __restrict__ W0g, const unsigned short* __restrict__ W1g,
    const float* __restrict__ b0, const float* __restrict__ b1,
    const float* __restrict__ W2, const float* __restrict__ b2v,
    float* __restrict__ out, int Npts)
{
  __shared__ unsigned short act[128 * 256];   // 64 KB, k-grouped layout

  const int tid = threadIdx.x;
  const int p0 = blockIdx.x * 128;

  // zero the kb=7 block (covers pad cols 227..255)
  {
    uint4 z = {0u, 0u, 0u, 0u};
    uint4* zb = (uint4*)(act + 7 * 4096);
    if (tid < 512) zb[tid] = z;
  }
  __syncthreads();

  // part A: copy x row -> net_in cols 0..130 (latents + coords)
  for (int idx = tid; idx < 128 * XDIM; idx += 512) {
    int r = idx / XDIM;
    int c = idx - r * XDIM;
    int p = p0 + r; if (p >= Npts) p = Npts - 1;
    float v = x[(size_t)p * XDIM + c];
    act[act_addr(r, c)] = f2bf(v);
  }

  // part B: triplane bilinear feats -> cols 131..226
  {
    int p_l = tid >> 2;
    int q = tid & 3;
    int p = p0 + p_l; if (p >= Npts) p = Npts - 1;
    float cc0 = x[(size_t)p * XDIM + LATENT + 0];
    float cc1 = x[(size_t)p * XDIM + LATENT + 1];
    float cc2 = x[(size_t)p * XDIM + LATENT + 2];
#pragma unroll
    for (int pl = 0; pl < 3; ++pl) {
      float u = (pl == 2) ? cc1 : cc0;
      float v = (pl == 0) ? cc1 : cc2;
      float gx = fminf(fmaxf((u + 1.f) * 256.f, 0.f), 512.f);
      float gy = fminf(fmaxf((v + 1.f) * 256.f, 0.f), 512.f);
      float x0f = floorf(gx), y0f = floorf(gy);
      int x0 = (int)x0f, y0 = (int)y0f;
      int x1 = min(x0 + 1, GSZ - 1), y1 = min(y0 + 1, GSZ - 1);
      float wx = gx - x0f, wy = gy - y0f;
      float w00 = (1.f - wx) * (1.f - wy), w01 = wx * (1.f - wy);
      float w10 = (1.f - wx) * wy,        w11 = wx * wy;
      float f[8];
      if (USE_PT) {
        const uint4 v00 = *(const uint4*)(Pt + ((size_t)((pl * GSZ + y0) * GSZ + x0)) * 32 + q * 8);
        const uint4 v01 = *(const uint4*)(Pt + ((size_t)((pl * GSZ + y0) * GSZ + x1)) * 32 + q * 8);
        const uint4 v10 = *(const uint4*)(Pt + ((size_t)((pl * GSZ + y1) * GSZ + x0)) * 32 + q * 8);
        const uint4 v11 = *(const uint4*)(Pt + ((size_t)((pl * GSZ + y1) * GSZ + x1)) * 32 + q * 8);
#pragma unroll
        for (int j = 0; j < 8; ++j) {
          f[j] = w00 * bf2f(((const unsigned short*)&v00)[j])
               + w01 * bf2f(((const unsigned short*)&v01)[j])
               + w10 * bf2f(((const unsigned short*)&v10)[j])
               + w11 * bf2f(((const unsigned short*)&v11)[j]);
        }
      } else {
#pragma unroll
        for (int j = 0; j < 8; ++j) {
          int c = q * 8 + j;
          const float* pc = P + (size_t)(pl * FDIM + c) * GSZ * GSZ;
          f[j] = w00 * pc[y0 * GSZ + x0] + w01 * pc[y0 * GSZ + x1]
               + w10 * pc[y1 * GSZ + x0] + w11 * pc[y1 * GSZ + x1];
        }
      }
#pragma unroll
      for (int j = 0; j < 8; ++j) {
        int c = XDIM + pl * FDIM + q * 8 + j;
        act[act_addr(p_l, c)] = f2bf(f[j]);
      }
    }
  }
  __syncthreads();

  const int lane = tid & 63, wid = tid >> 6;
  const int rg = wid >> 2, cg = wid & 3, lr = lane & 15, lg = lane >> 4;

  gemm_layer(act, W0g, b0, rg, cg, lr, lg);   // layer 0: K=256 (padded 227)
  gemm_layer(act, W1g, b1, rg, cg, lr, lg);   // layer 1: K=256

  // layer 2: h2 @ W2 + b2  (4 threads per point)
  {
    int p_l = tid >> 2, q = tid & 3;
    float sum = 0.f;
#pragma unroll
    for (int j = 0; j < 64; ++j) {
      int c = q * 64 + j;
      sum += bf2f(act[act_addr(p_l, c)]) * W2[c];
    }
    sum += __shfl_xor(sum, 1);
    sum += __shfl_xor(sum, 2);
    if (q == 0) {
      int p = p0 + p_l;
      if (p < Npts) out[p] = sum + b2v[0];
    }
  }
}

extern "C" void kernel_launch(void* const* d_in, const int* in_sizes, int n_in,
                              void* d_out, int out_size, void* d_ws, size_t ws_size,
                              hipStream_t stream)
{
  const float* x  = (const float*)d_in[0];
  const float* P  = (const float*)d_in[1];
  const float* W0 = (const float*)d_in[2];
  const float* b0 = (const float*)d_in[3];
  const float* W1 = (const float*)d_in[4];
  const float* b1 = (const float*)d_in[5];
  const float* W2 = (const float*)d_in[6];
  const float* b2 = (const float*)d_in[7];
  float* out = (float*)d_out;
  int Npts = in_sizes[0] / XDIM;

  const size_t PT_BYTES = (size_t)3 * GSZ * GSZ * 32 * 2;  // ~50.5 MB
  const size_t WG_BYTES = (size_t)8192 * 8 * 2;            // 128 KB each
  char* ws = (char*)d_ws;
  int use_pt = (ws_size >= PT_BYTES + 2 * WG_BYTES) ? 1 : 0;
  unsigned short *Ptb, *W0g, *W1g;
  if (use_pt) {
    Ptb = (unsigned short*)ws;
    W0g = (unsigned short*)(ws + PT_BYTES);
    W1g = (unsigned short*)(ws + PT_BYTES + WG_BYTES);
  } else {
    Ptb = nullptr;
    W0g = (unsigned short*)ws;
    W1g = (unsigned short*)(ws + WG_BYTES);
  }

  prep_w<<<64, 256, 0, stream>>>(W0, W1, W0g, W1g);
  if (use_pt) prep_pt<<<(3 * GSZ * GSZ + 255) / 256, 256, 0, stream>>>(P, Ptb);

  int nblk = (Npts + 127) / 128;
  if (use_pt)
    sdf_main<1><<<nblk, 512, 0, stream>>>(x, P, Ptb, W0g, W1g, b0, b1, W2, b2, out, Npts);
  else
    sdf_main<0><<<nblk, 512, 0, stream>>>(x, P, Ptb, W0g, W1g, b0, b1, W2, b2, out, Npts);
}